// Round 4
// baseline (310.315 us; speedup 1.0000x reference)
//
#include <hip/hip_runtime.h>
#include <stdint.h>

// MultiHeadAttention: B=4, S=2048, D_MODEL=1024, H=16, dh=64
// R4: all GEMMs -> m97 structure (bf16 operands, linear [128][32] LDS,
//     global_load_lds dwordx4 staging, 2-barrier K-loop). X pre-converted to
//     bf16 per-z through the ctx region (footprint stays 72MB). attn K/V
//     staging -> global_load_lds with pre-swizzled global source (rule #21).

typedef unsigned short u16;
typedef __attribute__((ext_vector_type(8))) short bf16x8;
typedef __attribute__((ext_vector_type(4))) float f32x4;

#define LOG2E 1.4426950408889634f

__device__ __forceinline__ u16 f2bf(float f) {
  uint32_t u = __builtin_bit_cast(uint32_t, f);
  u += 0x7fffu + ((u >> 16) & 1u);   // RNE
  return (u16)(u >> 16);
}
// packed f32x2 -> bf16x2 (RNE), single VALU op; no builtin on gfx950 (m240)
__device__ __forceinline__ uint32_t cvt_pk(float a, float b) {
  uint32_t r;
  asm("v_cvt_pk_bf16_f32 %0, %1, %2" : "=v"(r) : "v"(a), "v"(b));
  return r;
}
// async global->LDS, 16B per lane; LDS dest = wave-uniform base + lane*16
__device__ __forceinline__ void gload16(const u16* g, u16* l) {
  __builtin_amdgcn_global_load_lds(
      (const __attribute__((address_space(1))) uint32_t*)(const void*)g,
      (__attribute__((address_space(3))) uint32_t*)(void*)l, 16, 0, 0);
}

// ---------------- fp32 -> bf16 convert (per-z X panel) ----------------
__global__ __launch_bounds__(256) void convert_x(
    const float* __restrict__ X, u16* __restrict__ Xb)
{
  const size_t i = ((size_t)blockIdx.x * 256 + threadIdx.x) * 8;
  const float4 a = *(const float4*)(X + i);
  const float4 b = *(const float4*)(X + i + 4);
  uint4 o;
  o.x = cvt_pk(a.x, a.y); o.y = cvt_pk(a.z, a.w);
  o.z = cvt_pk(b.x, b.y); o.w = cvt_pk(b.z, b.w);
  *(uint4*)(Xb + i) = o;
}

// ---------------- weight transpose + bf16 convert ----------------
__global__ __launch_bounds__(256) void transpose_w(
    const float* __restrict__ W0, const float* __restrict__ W1,
    const float* __restrict__ W2, const float* __restrict__ W3,
    u16* __restrict__ Wt)
{
  const int z = blockIdx.z;
  const float* W = (z == 0) ? W0 : (z == 1) ? W1 : (z == 2) ? W2 : W3;
  u16* T = Wt + ((size_t)z << 20);
  const int n0 = blockIdx.x * 64, k0 = blockIdx.y * 64;
  const int tid = threadIdx.x;
  const int r = tid >> 4, c4 = (tid & 15) * 4;
  __shared__ float t[64][65];
#pragma unroll
  for (int j = 0; j < 4; ++j) {
    const int row = r + j * 16;
    const float4 v = *(const float4*)(W + (size_t)(k0 + row) * 1024 + n0 + c4);
    t[c4 + 0][row] = v.x; t[c4 + 1][row] = v.y;
    t[c4 + 2][row] = v.z; t[c4 + 3][row] = v.w;
  }
  __syncthreads();
#pragma unroll
  for (int j = 0; j < 4; ++j) {
    const int nrow = r + j * 16;
    uint2 o;
    o.x = cvt_pk(t[nrow][c4 + 0], t[nrow][c4 + 1]);
    o.y = cvt_pk(t[nrow][c4 + 2], t[nrow][c4 + 3]);
    *(uint2*)(T + (size_t)(n0 + nrow) * 1024 + k0 + c4) = o;
  }
}

// ---------------- projection GEMM (m97 structure) ----------------
// A bf16 [8192][1024] @ Wt bf16 [1024 n][1024 k] + bias.
// 128x128 tile, 4 waves x (64x64), BK=32, LDS linear [128][32],
// staging via 4x global_load_lds dwordx4 / thread / K-step.
// mode: 0=Q (scale, BHSd), 1=K (BHSd), 2=V^T (BHdS), 3=out fp32 [8192][1024].
__global__ __launch_bounds__(256) void gemm_proj(
    const u16* __restrict__ A, const u16* __restrict__ Wt,
    const float* __restrict__ Bi, u16* __restrict__ O16,
    float* __restrict__ O32, int mode)
{
  const int bid = blockIdx.x;
  const int nid = (bid & 7) * 64 + (bid >> 3);   // XCD-chunked (512 blocks)
  const int n0 = (nid & 7) * 128;
  const int m0 = (nid >> 3) * 128;
  const int tid = threadIdx.x;
  const int w = tid >> 6, l = tid & 63, lo = l & 15, hi = l >> 4;
  const int wr = w >> 1, wc = w & 1;

  __shared__ __align__(16) u16 As[128 * 32];
  __shared__ __align__(16) u16 Bs[128 * 32];

  const f32x4 fz = {0.f, 0.f, 0.f, 0.f};
  f32x4 acc[4][4];
#pragma unroll
  for (int m = 0; m < 4; ++m)
#pragma unroll
    for (int n = 0; n < 4; ++n) acc[m][n] = fz;

  // staging: wave w, instr j in {0,1}: rows w*32 + j*16 + (l>>2), slot (l&3)*8
  const int srow = w * 32 + (l >> 2);
  const u16* ga = A  + (size_t)(m0 + srow) * 1024 + (l & 3) * 8;
  const u16* gb = Wt + (size_t)(n0 + srow) * 1024 + (l & 3) * 8;
  u16* lA0 = &As[w * 1024];  u16* lA1 = &As[w * 1024 + 512];
  u16* lB0 = &Bs[w * 1024];  u16* lB1 = &Bs[w * 1024 + 512];

  for (int k0 = 0; k0 < 1024; k0 += 32) {
    __syncthreads();                      // prev frag reads done
    gload16(ga,             lA0);
    gload16(ga + 16 * 1024, lA1);
    gload16(gb,             lB0);
    gload16(gb + 16 * 1024, lB1);
    ga += 32; gb += 32;
    __syncthreads();                      // staging visible (vmcnt(0) drained)

    bf16x8 af[4], bf[4];
#pragma unroll
    for (int m = 0; m < 4; ++m)
      af[m] = *(const bf16x8*)&As[(wr * 64 + m * 16 + lo) * 32 + hi * 8];
#pragma unroll
    for (int n = 0; n < 4; ++n)
      bf[n] = *(const bf16x8*)&Bs[(wc * 64 + n * 16 + lo) * 32 + hi * 8];
#pragma unroll
    for (int m = 0; m < 4; ++m)
#pragma unroll
      for (int n = 0; n < 4; ++n)
        acc[m][n] = __builtin_amdgcn_mfma_f32_16x16x32_bf16(af[m], bf[n], acc[m][n], 0, 0, 0);
  }

#pragma unroll
  for (int m = 0; m < 4; ++m) {
#pragma unroll
    for (int n = 0; n < 4; ++n) {
      const int col = n0 + wc * 64 + n * 16 + lo;   // col = h*64 + d
      const float bc = Bi[col];
      const int h = col >> 6, d = col & 63;
#pragma unroll
      for (int i = 0; i < 4; ++i) {
        const int r = m0 + wr * 64 + m * 16 + hi * 4 + i;  // r = b*2048 + s
        const int b = r >> 11, s = r & 2047;
        float v = acc[m][n][i] + bc;
        if (mode == 0) {
          v *= 0.125f * LOG2E;  // fold 1/sqrt(dh) and log2(e)
          O16[((size_t)((b * 16 + h) * 2048 + s)) * 64 + d] = f2bf(v);
        } else if (mode == 1) {
          O16[((size_t)((b * 16 + h) * 2048 + s)) * 64 + d] = f2bf(v);
        } else if (mode == 2) {
          O16[((size_t)((b * 16 + h) * 64 + d)) * 2048 + s] = f2bf(v);
        } else {
          O32[(size_t)r * 1024 + col] = v;
        }
      }
    }
  }
}

// ---------------- flash attention ----------------
// 1-D grid 2048, XCD-chunked. K/V staged via global_load_lds (linear LDS dest)
// with pre-swizzled GLOBAL source: LDS(row, slot) holds global(row, slot^(row&7))
// so swizzled b128 reads are bank-spread (rule #21, T2/G4).
__global__ __launch_bounds__(256) void attn(
    const u16* __restrict__ Q, const u16* __restrict__ K,
    const u16* __restrict__ Vt, const float* __restrict__ mask,
    u16* __restrict__ Ctx)
{
  const int bid = blockIdx.x;
  const int nid = (bid & 7) * 256 + (bid >> 3);
  const int qt = nid & 31;
  const int bh = nid >> 5;
  const int b = bh >> 4, h = bh & 15;
  const int tid = threadIdx.x;
  const int w = tid >> 6, l = tid & 63, lo = l & 15, hi = l >> 4;

  __shared__ __align__(16) u16 Kl[64 * 64];
  __shared__ __align__(16) u16 Vl[64 * 64];
  __shared__ __align__(16) uint32_t Plw[4][32 * 20];

  const u16* Qb = Q + (size_t)bh * (2048 * 64);
  const u16* Kb = K + (size_t)bh * (2048 * 64);
  const u16* Vb = Vt + (size_t)bh * (64 * 2048);
  const float* mb = mask + (size_t)b * 2048;

  const int qrow = qt * 64 + w * 16 + lo;
  const bf16x8 qa0 = *(const bf16x8*)(Qb + (size_t)qrow * 64 + hi * 8);
  const bf16x8 qa1 = *(const bf16x8*)(Qb + (size_t)qrow * 64 + 32 + hi * 8);

  const f32x4 fz = {0.f, 0.f, 0.f, 0.f};
  f32x4 o[4] = {fz, fz, fz, fz};
  float mrun = -1e30f, lrun = 0.f;   // stats for q = lo (replicated over hi)

  uint32_t* Pw = &Plw[w][0];
  const int lo7 = lo & 7;
  const float MS = -1.0e9f * LOG2E;

  // staging source (pre-swizzled): lane l covers row w*16 + j*8 + (l>>3),
  // LDS slot l&7; global slot = (l&7) ^ (l>>3)  (row&7 == l>>3).
  const int r8 = l >> 3;
  const int sl = (l & 7) ^ r8;
  const u16* gK = Kb + (size_t)(w * 16 + r8) * 64 + sl * 8;
  const u16* gV = Vb + (size_t)(w * 16 + r8) * 2048 + sl * 8;
  u16* lK0 = &Kl[w * 1024];  u16* lK1 = &Kl[w * 1024 + 512];
  u16* lV0 = &Vl[w * 1024];  u16* lV1 = &Vl[w * 1024 + 512];

  for (int kt = 0; kt < 32; ++kt) {
    const int kv0 = kt * 64;
    float4 m4[4];
#pragma unroll
    for (int f = 0; f < 4; ++f)
      m4[f] = *(const float4*)(mb + kv0 + 16 * f + 4 * hi);

    __syncthreads();                      // prev tile's LDS reads done
    gload16(gK + (size_t)kv0 * 64,       lK0);
    gload16(gK + (size_t)kv0 * 64 + 512, lK1);   // rows +8
    gload16(gV + kv0,                    lV0);
    gload16(gV + kv0 + 8 * 2048,         lV1);   // rows +8
    __syncthreads();                      // staging visible

    // S^T[kv][q]: kv = 16f + 4hi + i, q = lo (log2-domain; scale folded in Q)
    f32x4 st[4];
    __builtin_amdgcn_s_setprio(1);
#pragma unroll
    for (int f = 0; f < 4; ++f) {
      const int krow = (f * 16 + lo) * 64;
      const bf16x8 kb0 = *(const bf16x8*)&Kl[krow + ((hi ^ lo7) << 3)];
      const bf16x8 kb1 = *(const bf16x8*)&Kl[krow + (((4 + hi) ^ lo7) << 3)];
      f32x4 a = __builtin_amdgcn_mfma_f32_16x16x32_bf16(kb0, qa0, fz, 0, 0, 0);
      st[f] = __builtin_amdgcn_mfma_f32_16x16x32_bf16(kb1, qa1, a, 0, 0, 0);
    }
    __builtin_amdgcn_s_setprio(0);

    // add mask, block-max for row q=lo
    float mx = -1e30f;
#pragma unroll
    for (int f = 0; f < 4; ++f) {
      st[f][0] += m4[f].x * MS; st[f][1] += m4[f].y * MS;
      st[f][2] += m4[f].z * MS; st[f][3] += m4[f].w * MS;
      mx = fmaxf(mx, fmaxf(fmaxf(st[f][0], st[f][1]), fmaxf(st[f][2], st[f][3])));
    }
    mx = fmaxf(mx, __shfl_xor(mx, 16));
    mx = fmaxf(mx, __shfl_xor(mx, 32));

    // defer-max: only rescale when max grew by > 8 (exp2 domain, bound 256)
    if (!__all(mx - mrun <= 8.0f)) {
      const float mn = fmaxf(mrun, mx);
      const float sc = exp2f(mrun - mn);
      mrun = mn;
      lrun *= sc;
      float scq[4];
#pragma unroll
      for (int i = 0; i < 4; ++i) scq[i] = __shfl(sc, hi * 4 + i);
#pragma unroll
      for (int nf = 0; nf < 4; ++nf) {
        o[nf][0] *= scq[0]; o[nf][1] *= scq[1];
        o[nf][2] *= scq[2]; o[nf][3] *= scq[3];
      }
    }

    // P = exp2(S - m), cvt_pk to bf16 pairs, per-lane row-sum
    float rs = 0.f;
#pragma unroll
    for (int f = 0; f < 4; ++f) {
      const float p0 = exp2f(st[f][0] - mrun);
      const float p1 = exp2f(st[f][1] - mrun);
      const float p2 = exp2f(st[f][2] - mrun);
      const float p3 = exp2f(st[f][3] - mrun);
      rs += (p0 + p1) + (p2 + p3);
      const int t = 8 * f + 2 * hi;           // kv-pair index
      Pw[t * 20 + lo] = cvt_pk(p0, p1);
      Pw[(t + 1) * 20 + lo] = cvt_pk(p2, p3);
    }
    rs += __shfl_xor(rs, 16);
    rs += __shfl_xor(rs, 32);
    lrun += rs;

    __builtin_amdgcn_wave_barrier();  // keep P writes before P reads

    // gather P A-frags: lane needs P[q=lo][kv = kk*32 + 8hi + j]
    union { uint32_t u[4]; bf16x8 v; } pa0, pa1;
#pragma unroll
    for (int u = 0; u < 4; ++u) {
      pa0.u[u] = Pw[(4 * hi + u) * 20 + lo];
      pa1.u[u] = Pw[(16 + 4 * hi + u) * 20 + lo];
    }

    // PV: O[q][d] += P(16x64) @ V(64x64)
    __builtin_amdgcn_s_setprio(1);
#pragma unroll
    for (int nf = 0; nf < 4; ++nf) {
      const int vrow = (nf * 16 + lo) * 64;
      const bf16x8 vb0 = *(const bf16x8*)&Vl[vrow + ((hi ^ lo7) << 3)];
      const bf16x8 vb1 = *(const bf16x8*)&Vl[vrow + (((4 + hi) ^ lo7) << 3)];
      o[nf] = __builtin_amdgcn_mfma_f32_16x16x32_bf16(pa0.v, vb0, o[nf], 0, 0, 0);
      o[nf] = __builtin_amdgcn_mfma_f32_16x16x32_bf16(pa1.v, vb1, o[nf], 0, 0, 0);
    }
    __builtin_amdgcn_s_setprio(0);
  }

  const float linv = 1.f / lrun;
  float invq[4];
#pragma unroll
  for (int i = 0; i < 4; ++i) invq[i] = __shfl(linv, hi * 4 + i);
#pragma unroll
  for (int nf = 0; nf < 4; ++nf) {
#pragma unroll
    for (int i = 0; i < 4; ++i) {
      const int s = qt * 64 + w * 16 + hi * 4 + i;
      const int d = nf * 16 + lo;
      Ctx[((size_t)((b * 2048 + s) * 16 + h)) * 64 + d] = f2bf(o[nf][i] * invq[i]);
    }
  }
}

extern "C" void kernel_launch(void* const* d_in, const int* in_sizes, int n_in,
                              void* d_out, int out_size, void* d_ws, size_t ws_size,
                              hipStream_t stream) {
  const float* q_in = (const float*)d_in[0];
  const float* k_in = (const float*)d_in[1];
  const float* v_in = (const float*)d_in[2];
  const float* mask = (const float*)d_in[3];
  const float* wq = (const float*)d_in[4];
  const float* bq = (const float*)d_in[5];
  const float* wk = (const float*)d_in[6];
  const float* bk = (const float*)d_in[7];
  const float* wv = (const float*)d_in[8];
  const float* bv = (const float*)d_in[9];
  const float* wo = (const float*)d_in[10];
  const float* bo = (const float*)d_in[11];

  // workspace (72MB): wT 8MB | Q 16MB | K 16MB | Vt 16MB | xbf/ctx 16MB
  u16* ws  = (u16*)d_ws;
  u16* wtq = ws;
  u16* wtk = wtq + (1u << 20);
  u16* wtv = wtk + (1u << 20);
  u16* wto = wtv + (1u << 20);
  u16* Qb  = wto + (1u << 20);
  u16* Kb  = Qb + (size_t)8192 * 1024;
  u16* Vtb = Kb + (size_t)8192 * 1024;
  u16* xbf = Vtb + (size_t)8192 * 1024;  // doubles as ctx (dead by attn time)
  u16* ctx = xbf;

  transpose_w<<<dim3(16, 16, 4), 256, 0, stream>>>(wq, wk, wv, wo, wtq);

  convert_x<<<4096, 256, 0, stream>>>(q_in, xbf);
  gemm_proj<<<512, 256, 0, stream>>>(xbf, wtq, bq, Qb, nullptr, 0);
  convert_x<<<4096, 256, 0, stream>>>(k_in, xbf);
  gemm_proj<<<512, 256, 0, stream>>>(xbf, wtk, bk, Kb, nullptr, 1);
  convert_x<<<4096, 256, 0, stream>>>(v_in, xbf);
  gemm_proj<<<512, 256, 0, stream>>>(xbf, wtv, bv, Vtb, nullptr, 2);

  attn<<<2048, 256, 0, stream>>>(Qb, Kb, Vtb, mask, ctx);

  gemm_proj<<<512, 256, 0, stream>>>(ctx, wto, bo, nullptr, (float*)d_out, 3);
}